// Round 19
// baseline (181.824 us; speedup 1.0000x reference)
//
#include <hip/hip_runtime.h>
#include <hip/hip_bf16.h>

#define D_MODEL 1024
#define ATT_DIM 64
#define BATCH 8
#define SEQ 2048
#define MROWS (BATCH * SEQ)  // 16384

typedef short bf16x8 __attribute__((ext_vector_type(8)));
typedef float f32x4 __attribute__((ext_vector_type(4)));

#define MFMA16(a, b, c) __builtin_amdgcn_mfma_f32_16x16x32_bf16((a), (b), (c), 0, 0, 0)

__device__ inline short f2bf(float f) {
    union { __hip_bfloat16 h; short s; } u;
    u.h = __float2bfloat16(f);  // RNE
    return u.s;
}

// pack two f32 -> one dword of 2 bf16 (RNE); lo in low half
__device__ __forceinline__ unsigned cvtpk(float lo, float hi) {
    unsigned r;
    asm("v_cvt_pk_bf16_f32 %0, %1, %2" : "=v"(r) : "v"(lo), "v"(hi));
    return r;
}

// ---------------------------------------------------------------------------
// K0: convert Wq,Wk,Wv fp32 -> bf16 workspace [3][64][1024].
// Wq pre-scaled by 1/64 (exact pow2) so MFMA output == scores.
// ---------------------------------------------------------------------------
__global__ __launch_bounds__(256) void wcvt_kernel(
    const float* __restrict__ Wq, const float* __restrict__ Wk,
    const float* __restrict__ Wv, short* __restrict__ Wbf)
{
    const int idx = blockIdx.x * 256 + threadIdx.x;   // 24576 threads
    const int per = ATT_DIM * D_MODEL;                // 65536
    const int base = idx * 8;
    const int mi = base / per;
    const int off = base - mi * per;
    const float* src = (mi == 0) ? Wq : (mi == 1 ? Wk : Wv);
    const float sc = (mi == 0) ? (1.0f / 64.0f) : 1.0f;
    const float4 a = *reinterpret_cast<const float4*>(src + off);
    const float4 b = *reinterpret_cast<const float4*>(src + off + 4);
    bf16x8 r;
    r[0] = f2bf(a.x * sc); r[1] = f2bf(a.y * sc);
    r[2] = f2bf(a.z * sc); r[3] = f2bf(a.w * sc);
    r[4] = f2bf(b.x * sc); r[5] = f2bf(b.y * sc);
    r[6] = f2bf(b.z * sc); r[7] = f2bf(b.w * sc);
    *reinterpret_cast<bf16x8*>(Wbf + base) = r;
}

// ---------------------------------------------------------------------------
// K1a: projection PARTIALS, k-split x4, max-occupancy (TLP test).
// Block = 256 thr = 4 waves; wave w owns 16 rows x K-quarter [w*256,+256).
// No LDS, no barriers, no inter-wave coupling. Grid (MROWS/16, 3) = 3072
// blocks -> thread-capped 8 blocks/CU = 32 waves/CU (100% occupancy).
// __launch_bounds__(256, 8) caps VGPR at 64 so the cap is reachable.
// Each wave: 8 chunks x {2 float4 A-loads, cvt_pk pack, 4 W-frag loads
// (L2-hot), 4 MFMA}; fp32 partial acc written to part[mat*4+w].
// ---------------------------------------------------------------------------
__global__ __launch_bounds__(256, 8) void proj_part_kernel(
    const float* __restrict__ q, const float* __restrict__ k,
    const float* __restrict__ v, const short* __restrict__ Wbf,
    float* __restrict__ part)
{
    const int mat = blockIdx.y;  // 0:q 1:k 2:v
    const float* x = (mat == 0) ? q : (mat == 1 ? k : v);
    const short* W = Wbf + mat * ATT_DIM * D_MODEL;

    const int tid = threadIdx.x;
    const int w = tid >> 6;    // 0..3 = K-quarter
    const int l = tid & 63;
    const int lr = l & 15;
    const int g = l >> 4;

    const int m0 = blockIdx.x * 16;
    const int kq = w * 256;

    const float* xrow = x + (long)(m0 + lr) * D_MODEL + kq + g * 8;
    const short* wb0 = W + (0 * 16 + lr) * D_MODEL + kq + g * 8;
    const short* wb1 = W + (1 * 16 + lr) * D_MODEL + kq + g * 8;
    const short* wb2 = W + (2 * 16 + lr) * D_MODEL + kq + g * 8;
    const short* wb3 = W + (3 * 16 + lr) * D_MODEL + kq + g * 8;

    f32x4 acc[4] = {};

    #pragma unroll
    for (int c = 0; c < 8; ++c) {
        const float4 a0 = *reinterpret_cast<const float4*>(xrow + c * 32);
        const float4 a1 = *reinterpret_cast<const float4*>(xrow + c * 32 + 4);
        union { uint4 u4; bf16x8 v8; } afu;
        afu.u4.x = cvtpk(a0.x, a0.y);
        afu.u4.y = cvtpk(a0.z, a0.w);
        afu.u4.z = cvtpk(a1.x, a1.y);
        afu.u4.w = cvtpk(a1.z, a1.w);
        const bf16x8 af = afu.v8;
        acc[0] = MFMA16(af, *reinterpret_cast<const bf16x8*>(wb0 + c * 32), acc[0]);
        acc[1] = MFMA16(af, *reinterpret_cast<const bf16x8*>(wb1 + c * 32), acc[1]);
        acc[2] = MFMA16(af, *reinterpret_cast<const bf16x8*>(wb2 + c * 32), acc[2]);
        acc[3] = MFMA16(af, *reinterpret_cast<const bf16x8*>(wb3 + c * 32), acc[3]);
    }

    // D layout: row = m0 + g*4 + j, col = lr (within 16-col tile ef)
    float* pout = part + ((long)(mat * 4 + w) * MROWS) * ATT_DIM;
    #pragma unroll
    for (int ef = 0; ef < 4; ++ef)
        #pragma unroll
        for (int j = 0; j < 4; ++j)
            pout[(long)(m0 + g * 4 + j) * ATT_DIM + ef * 16 + lr] = acc[ef][j];
}

// ---------------------------------------------------------------------------
// K1b: merge partials -> bf16 qp/kp and transposed vpT.
// Grid (MROWS/64, 3), block 256. Each thread sums 4 quarters for 16
// elements. mat<2: direct coalesced bf16 stores. mat==2: stage in LDS
// tile[e][row] (conflict-free: stride 65), then write vpT rows coalesced.
// ---------------------------------------------------------------------------
__global__ __launch_bounds__(256) void proj_merge_kernel(
    const float* __restrict__ part,
    short* __restrict__ qp, short* __restrict__ kp, short* __restrict__ vpT)
{
    __shared__ float vt[64][65];

    const int mat = blockIdx.y;
    const int m0 = blockIdx.x * 64;
    const int tid = threadIdx.x;

    const float* p0 = part + ((long)(mat * 4 + 0) * MROWS + m0) * ATT_DIM;
    const float* p1 = part + ((long)(mat * 4 + 1) * MROWS + m0) * ATT_DIM;
    const float* p2 = part + ((long)(mat * 4 + 2) * MROWS + m0) * ATT_DIM;
    const float* p3 = part + ((long)(mat * 4 + 3) * MROWS + m0) * ATT_DIM;

    if (mat < 2) {
        short* out = (mat == 0) ? qp : kp;
        #pragma unroll
        for (int i = 0; i < 16; ++i) {
            const int idx = i * 256 + tid;            // row = idx>>6, e = idx&63
            const float s = p0[idx] + p1[idx] + p2[idx] + p3[idx];
            out[(long)m0 * ATT_DIM + idx] = f2bf(s);
        }
    } else {
        #pragma unroll
        for (int i = 0; i < 16; ++i) {
            const int idx = i * 256 + tid;
            const int row = idx >> 6, e = idx & 63;
            vt[e][row] = p0[idx] + p1[idx] + p2[idx] + p3[idx];
        }
        __syncthreads();
        const int b = m0 / SEQ;                       // 64-row block within one batch
        const int s0 = m0 - b * SEQ;
        #pragma unroll
        for (int i = 0; i < 16; ++i) {
            const int idx = i * 256 + tid;
            const int e = idx >> 6, so = idx & 63;
            vpT[((long)b * ATT_DIM + e) * SEQ + s0 + so] = f2bf(vt[e][so]);
        }
    }
}

// ---------------------------------------------------------------------------
// K2: fused scores+softmax+PV (byte-identical to r18 — hardware-verified).
// ---------------------------------------------------------------------------
union AttnSmem {
    float panel[8][16][128];   // 64 KB: per-wave P store panel (swizzled)
    float o[8][64][17];        // 34.8 KB: [wave][e][q] for final merge
};

__global__ __launch_bounds__(512, 4) void attn_kernel(
    const short* __restrict__ qp, const short* __restrict__ kp,
    const short* __restrict__ vpT, float* __restrict__ probs,
    float* __restrict__ att)
{
    __shared__ __align__(16) AttnSmem u;
    __shared__ float stats_l[8][16];

    const int tid = threadIdx.x;
    const int w = tid >> 6;    // 0..7
    const int l = tid & 63;
    const int lr = l & 15;
    const int g = l >> 4;

    const int b = blockIdx.y;
    const int q0 = blockIdx.x * 16;

    const short* qpb = qp + ((long)b * SEQ + q0) * ATT_DIM;
    const short* kpb = kp + (long)b * SEQ * ATT_DIM;
    const short* vTb = vpT + (long)b * ATT_DIM * SEQ;

    const bf16x8 qa0 = *reinterpret_cast<const bf16x8*>(qpb + lr * ATT_DIM + g * 8);
    const bf16x8 qa1 = *reinterpret_cast<const bf16x8*>(qpb + lr * ATT_DIM + 32 + g * 8);

    const int kbeg = w * 256;

    // ---------------- pass A: swapped QK^T (pure loads+MFMA) ----------------
    f32x4 s[8][2];
    #pragma unroll
    for (int ch = 0; ch < 8; ++ch) {
        const short* kb = kpb + (long)(kbeg + ch * 32) * ATT_DIM;
        const bf16x8 kb00 = *reinterpret_cast<const bf16x8*>(kb + lr * ATT_DIM + g * 8);
        const bf16x8 kb01 = *reinterpret_cast<const bf16x8*>(kb + lr * ATT_DIM + 32 + g * 8);
        const bf16x8 kb10 = *reinterpret_cast<const bf16x8*>(kb + (16 + lr) * ATT_DIM + g * 8);
        const bf16x8 kb11 = *reinterpret_cast<const bf16x8*>(kb + (16 + lr) * ATT_DIM + 32 + g * 8);
        f32x4 t0 = {}; t0 = MFMA16(kb00, qa0, t0); t0 = MFMA16(kb01, qa1, t0);
        f32x4 t1 = {}; t1 = MFMA16(kb10, qa0, t1); t1 = MFMA16(kb11, qa1, t1);
        s[ch][0] = t0; s[ch][1] = t1;
    }

    // ---------------- softmax denominator (no max-sub; q = lr) --------------
    float lw = 0.f;
    #pragma unroll
    for (int ch = 0; ch < 8; ++ch)
        #pragma unroll
        for (int h = 0; h < 2; ++h)
            #pragma unroll
            for (int j = 0; j < 4; ++j) {
                const float e = __expf(s[ch][h][j]);
                s[ch][h][j] = e;
                lw += e;
            }
    lw += __shfl_xor(lw, 16);
    lw += __shfl_xor(lw, 32);

    if (l < 16) stats_l[w][l] = lw;
    __syncthreads();   // single softmax barrier

    float tot = 0.f;
    #pragma unroll
    for (int ww = 0; ww < 8; ++ww) tot += stats_l[ww][lr];
    const float inv = 1.0f / tot;
    #pragma unroll
    for (int ch = 0; ch < 8; ++ch)
        #pragma unroll
        for (int h = 0; h < 2; ++h)
            s[ch][h] *= inv;

    // ---------------- pass B: LDS-coalesced probs stores + PV ---------------
    f32x4 accO[4] = {};
    const bool hi2 = (g & 2) != 0;
    const bool swp = ((g ^ (g >> 1)) & 1) != 0;
    const bool odd = (g & 1) != 0;

    #pragma unroll
    for (int ch = 0; ch < 8; ++ch) {
        const int k0 = kbeg + ch * 32;

        // write normalized panel to LDS (swizzled; wave-local)
        {
            const int c0 = (ch & 3) * 32 + g * 4;       // col in 128-wide panel
            char* base = (char*)&u.panel[w][0][0] + lr * 512;
            *reinterpret_cast<f32x4*>(base + ((c0 * 4) ^ ((lr & 7) << 4))) = s[ch][0];
            *reinterpret_cast<f32x4*>(base + (((c0 + 16) * 4) ^ ((lr & 7) << 4))) = s[ch][1];
        }

        // pack to bf16 pairs: xy = (P[4g..4g+3]), zw = (P[16+4g..16+4g+3])
        const unsigned xy0 = cvtpk(s[ch][0][0], s[ch][0][1]);
        const unsigned xy1 = cvtpk(s[ch][0][2], s[ch][0][3]);
        const unsigned zw0 = cvtpk(s[ch][1][0], s[ch][1][1]);
        const unsigned zw1 = cvtpk(s[ch][1][2], s[ch][1][3]);

        // 4x4 dword transpose among lanes {lr, lr+16, lr+32, lr+48}:
        const unsigned s1a = hi2 ? xy0 : zw0;
        const unsigned s1b = hi2 ? xy1 : zw1;
        const unsigned r1a = __shfl_xor(s1a, 32);
        const unsigned r1b = __shfl_xor(s1b, 32);
        const unsigned p1a = hi2 ? zw0 : xy0;   // own U[g][g>>1]
        const unsigned p1b = hi2 ? zw1 : xy1;
        const unsigned s2a = swp ? p1a : r1a;
        const unsigned s2b = swp ? p1b : r1b;
        const unsigned r2a = __shfl_xor(s2a, 16);
        const unsigned r2b = __shfl_xor(s2b, 16);
        const unsigned ka = swp ? r1a : p1a;    // kept unit
        const unsigned kb_ = swp ? r1b : p1b;
        const unsigned d0 = odd ? r2a : ka;
        const unsigned d1 = odd ? r2b : kb_;
        const unsigned d2 = odd ? ka : r2a;
        const unsigned d3 = odd ? kb_ : r2b;
        union { uint4 u4; bf16x8 v; } pbu;
        pbu.u4 = make_uint4(d0, d1, d2, d3);
        const bf16x8 pb = pbu.v;   // = P[k0+8g+i][q0+lr], i=0..7

        #pragma unroll
        for (int ef = 0; ef < 4; ++ef) {
            const bf16x8 va = *reinterpret_cast<const bf16x8*>(
                vTb + (long)(ef * 16 + lr) * SEQ + k0 + g * 8);
            accO[ef] = MFMA16(va, pb, accO[ef]);
        }

        // flush half-panel as coalesced 512B runs (wave-local RAW via lgkmcnt)
        if ((ch & 3) == 3) {
            const int half = ch >> 2;
            #pragma unroll
            for (int j = 0; j < 8; ++j) {
                const int r = j * 2 + (l >> 5);
                const int cb = ((l & 31) * 16) ^ ((r & 7) << 4);
                const f32x4 val = *reinterpret_cast<const f32x4*>(
                    (const char*)&u.panel[w][0][0] + r * 512 + cb);
                *reinterpret_cast<f32x4*>(
                    probs + ((long)b * SEQ + q0 + r) * SEQ + kbeg + half * 128 +
                    (l & 31) * 4) = val;
            }
        }
    }

    // ---------------- merge O across waves ----------------
    __syncthreads();   // all panel reads done; union becomes u.o
    #pragma unroll
    for (int ef = 0; ef < 4; ++ef)
        #pragma unroll
        for (int j = 0; j < 4; ++j)
            u.o[w][ef * 16 + g * 4 + j][lr] = accO[ef][j];
    __syncthreads();

    {
        const int qr = tid >> 5;          // 0..15
        const int e0 = (tid & 31) * 2;    // 0..62
        float o0 = 0.f, o1 = 0.f;
        #pragma unroll
        for (int ww = 0; ww < 8; ++ww) {
            o0 += u.o[ww][e0][qr];
            o1 += u.o[ww][e0 + 1][qr];
        }
        float2 o = make_float2(o0, o1);
        *reinterpret_cast<float2*>(att + ((long)b * SEQ + q0 + qr) * ATT_DIM + e0) = o;
    }
}

// ---------------------------------------------------------------------------
extern "C" void kernel_launch(void* const* d_in, const int* in_sizes, int n_in,
                              void* d_out, int out_size, void* d_ws, size_t ws_size,
                              hipStream_t stream)
{
    const float* q  = (const float*)d_in[0];
    const float* k  = (const float*)d_in[1];
    const float* v  = (const float*)d_in[2];
    const float* Wq = (const float*)d_in[3];
    const float* Wk = (const float*)d_in[4];
    const float* Wv = (const float*)d_in[5];

    float* att   = (float*)d_out;                        // [B,S,64]
    float* probs = att + (size_t)BATCH * SEQ * ATT_DIM;  // [B,S,S]

    short* qp  = (short*)d_ws;                    // [B*S,64] bf16 (Wq pre-scaled 1/64)
    short* kp  = qp + (size_t)MROWS * ATT_DIM;    // [B*S,64] bf16
    short* vpT = kp + (size_t)MROWS * ATT_DIM;    // [B][64][S] bf16
    short* Wbf = vpT + (size_t)MROWS * ATT_DIM;   // [3][64][1024] bf16
    float* part = (float*)(Wbf + (size_t)3 * ATT_DIM * D_MODEL);  // [12][MROWS][64] f32

    wcvt_kernel<<<dim3(96), 256, 0, stream>>>(Wq, Wk, Wv, Wbf);

    proj_part_kernel<<<dim3(MROWS / 16, 3), 256, 0, stream>>>(
        q, k, v, Wbf, part);

    proj_merge_kernel<<<dim3(MROWS / 64, 3), 256, 0, stream>>>(
        part, qp, kp, vpT);

    attn_kernel<<<dim3(SEQ / 16, BATCH), 512, 0, stream>>>(
        qp, kp, vpT, probs, att);
}